// Round 8
// baseline (777.206 us; speedup 1.0000x reference)
//
#include <hip/hip_runtime.h>
#include <stdint.h>

typedef __attribute__((ext_vector_type(4))) float  floatx4;
typedef __attribute__((ext_vector_type(4))) uint32_t uintx4;
typedef __bf16 bf16x8 __attribute__((ext_vector_type(8)));

#define N_ROWS 131072
#define SCALE 0.044194173824159216f   /* 1/sqrt(512) */
#define GAP_T 1e-4f                   /* bf16-z worst-case err ~3e-5; margin 3x */

/* bank-spread slot for 64B rows: rows r..r+15 hit each 16B bank-group 2-way */
#define SLOT(c) ((((c) & 3) ^ (((c) >> 2) & 3)) << 4)

static __device__ __forceinline__ uint32_t bf16_rne(float x) {
    uint32_t u = __float_as_uint(x);
    return (u + 0x7FFFu + ((u >> 16) & 1u)) >> 16;
}

static __device__ __forceinline__ void gl_lds16(const void* g, void* l) {
    __builtin_amdgcn_global_load_lds(
        (const __attribute__((address_space(1))) void*)g,
        (__attribute__((address_space(3))) void*)l, 16, 0, 0);
}

static __device__ __forceinline__ bool better(float za, int ia, float zb, int ib) {
    return (za > zb) || (za == zb && ia < ib);
}

// ---------------------------------------------------------------------------
// Prep: E (f32 [512][512]) -> 32 pre-swizzled bf16 images of 16KB.
// Image img = ck*2 + h: k-chunk ck (32 k's), column half h (256 codes).
// LDS layout: byte(c', kb) = c'*64 + (kb ^ SLOT(c')), c' = col within half.
// ---------------------------------------------------------------------------
__global__ __launch_bounds__(256)
void prep_b(const float* __restrict__ E, uint32_t* __restrict__ bImg) {
    int w   = blockIdx.x * 256 + threadIdx.x;  // 0..131071 u32 words
    int img = w >> 12;                          // 4096 words per 16KB image
    int o   = (w & 4095) << 2;                  // byte offset in image
    int cp  = o >> 6;                           // col-in-half 0..255
    int kb  = (o & 63) ^ SLOT(cp);              // unswizzled k-byte
    int d   = ((img >> 1) << 5) + (kb >> 1);
    int col = ((img & 1) << 8) + cp;
    float x0 = E[col * 512 + d];
    float x1 = E[col * 512 + d + 1];
    bImg[w] = bf16_rne(x0) | (bf16_rne(x1) << 16);
}

// ---------------------------------------------------------------------------
// Fused: block = 64 rows x 512 codes, 4 waves (cg = col group of 128).
// LDS 40KB -> 4 blocks/CU (phase-decorrelated). 2-phase pipeline over 32
// stages (16 k-chunks x 2 col-halves, 16KB B images); A staged once per
// k-chunk, A-frags reused across both halves. Epilogue: 4 batches of 16 rows
// LDS-transposed to row-contiguous; softmax->dist, top2(s+g); final pass:
// near-tie exact-f32 fallback + out = E[idx] (straight-through val == 1.0).
// ---------------------------------------------------------------------------
__global__ __launch_bounds__(256, 4)
void fused(const float* __restrict__ X, const float* __restrict__ E,
           const float* __restrict__ G, const uint32_t* __restrict__ bImg,
           float* __restrict__ outp, float* __restrict__ dist) {
    __shared__ uint8_t lds[40960];
    // K: B par0 @0 (16K), B par1 @16384, A par0 @32768 (4K), A par1 @36864
    // Epi: transpose @0 (32K), stats @32768 (1K)
    const int t    = threadIdx.x;        // 0..255
    const int lane = t & 63;
    const int l15  = lane & 15;
    const int q    = lane >> 4;
    const int cg   = t >> 6;             // wave = col group
    const int row0 = blockIdx.x << 6;

    floatx4 acc[2][4][4];                // [h][nc][mi]
#pragma unroll
    for (int h = 0; h < 2; ++h)
#pragma unroll
        for (int nc = 0; nc < 4; ++nc)
#pragma unroll
            for (int mi = 0; mi < 4; ++mi) acc[h][nc][mi] = (floatx4)0.0f;

    // ---- staging geometry ----
    const int r_ld = t >> 2;             // A-stage row 0..63
    const int k8   = (t & 3) << 3;       // A-stage k elems (8)
    const float* xrow = X + (size_t)(row0 + r_ld) * 512 + k8;
    const int abyte = (r_ld << 6) + ((k8 << 1) ^ SLOT(r_ld));

#define STAGE_B(img, par) {                                                  \
    const uint8_t* src_ = (const uint8_t*)bImg + ((img) << 14);              \
    _Pragma("unroll")                                                        \
    for (int i_ = 0; i_ < 4; ++i_) {                                         \
        int off_ = (i_ << 12) + (t << 4);                                    \
        gl_lds16(src_ + off_, &lds[((par) << 14) + off_]);                   \
    } }

#define WRITE_A(v0, v1, par) {                                               \
    uintx4 hv_;                                                              \
    hv_.x = bf16_rne((v0).x) | (bf16_rne((v0).y) << 16);                     \
    hv_.y = bf16_rne((v0).z) | (bf16_rne((v0).w) << 16);                     \
    hv_.z = bf16_rne((v1).x) | (bf16_rne((v1).y) << 16);                     \
    hv_.w = bf16_rne((v1).z) | (bf16_rne((v1).w) << 16);                     \
    *(uintx4*)&lds[32768 + ((par) << 12) + abyte] = hv_; }

    // hh literal 0/1; apar runtime (LDS addr only); reload literal 0/1
#define COMPUTE(hh, apar, reload) {                                          \
    const int aoff_ = 32768 + ((apar) << 12);                                \
    if (reload) {                                                            \
        _Pragma("unroll")                                                    \
        for (int mi_ = 0; mi_ < 4; ++mi_) {                                  \
            int r_ = (mi_ << 4) + l15;                                       \
            af[mi_] = *(const bf16x8*)&lds[aoff_ + (r_ << 6) + ((q << 4) ^ SLOT(r_))]; \
        }                                                                    \
    }                                                                        \
    _Pragma("unroll")                                                        \
    for (int nc_ = 0; nc_ < 4; ++nc_) {                                      \
        int cp_ = (cg << 6) + (nc_ << 4) + l15;                              \
        bf16x8 b_ = *(const bf16x8*)&lds[((hh) << 14) + (cp_ << 6) + ((q << 4) ^ SLOT(cp_))]; \
        _Pragma("unroll")                                                    \
        for (int mi_ = 0; mi_ < 4; ++mi_)                                    \
            acc[hh][nc_][mi_] = __builtin_amdgcn_mfma_f32_16x16x32_bf16(af[mi_], b_, acc[hh][nc_][mi_], 0, 0, 0); \
    } }

    // ---- prologue: stage (ck0,h0); A(ck0); X regs for ck1 ----
    floatx4 xa0 = *(const floatx4*)(xrow);
    floatx4 xa1 = *(const floatx4*)(xrow + 4);
    STAGE_B(0, 0);
    WRITE_A(xa0, xa1, 0);
    xa0 = *(const floatx4*)(xrow + 32);
    xa1 = *(const floatx4*)(xrow + 36);
    __syncthreads();

    bf16x8 af[4];
    for (int ck = 0; ck < 16; ++ck) {
        // h=0 body: stage (ck,h1)->par1; compute (ck,h0) from par0
        STAGE_B((ck << 1) + 1, 1);
        COMPUTE(0, ck & 1, 1);
        __syncthreads();
        // h=1 body: stage (ck+1,h0)->par0; A(ck+1); X(ck+2); compute (ck,h1)
        if (ck + 1 < 16) {
            STAGE_B((ck + 1) << 1, 0);
            WRITE_A(xa0, xa1, (ck + 1) & 1);
        }
        if (ck + 2 < 16) {
            xa0 = *(const floatx4*)(xrow + ((ck + 2) << 5));
            xa1 = *(const floatx4*)(xrow + ((ck + 2) << 5) + 4);
        }
        COMPUTE(1, ck & 1, 0);
        __syncthreads();
    }

#pragma unroll
    for (int h = 0; h < 2; ++h)
#pragma unroll
        for (int nc = 0; nc < 4; ++nc)
#pragma unroll
            for (int mi = 0; mi < 4; ++mi) acc[h][nc][mi] *= SCALE;

    // -------- epilogue: 4 batches of 16 rows (batch bt <=> mi=bt) ---------
    float* fZ1 = (float*)(lds + 32768);          // [64]
    int*   fI1 = (int*)  (lds + 33024);
    float* fZ2 = (float*)(lds + 33280);
    int*   fI2 = (int*)  (lds + 33536);

    const int rp = t >> 4;    // 0..15 transposed row slot
    const int tc = t & 15;    // 16 threads per row

#pragma unroll
    for (int bt = 0; bt < 4; ++bt) {
        // transpose-write rows bt*16..+16: all waves (cols by cg,h,nc)
#pragma unroll
        for (int h = 0; h < 2; ++h)
#pragma unroll
            for (int nc = 0; nc < 4; ++nc) {
                int col = (h << 8) + (cg << 6) + (nc << 4) + l15;
#pragma unroll
                for (int p = 0; p < 4; ++p) {
                    int lr = (q << 2) + p;       // 0..15
                    *(float*)&lds[(lr << 11) + ((col << 2) ^ ((lr & 7) << 4))] = acc[h][nc][bt][p];
                }
            }
        __syncthreads();

        const int row = (bt << 4) + rp;          // local 0..63
        const int gr  = row0 + row;
        const float* gp = G + (size_t)gr * 512 + (tc << 2);
        floatx4 g[8];
#pragma unroll
        for (int k = 0; k < 8; ++k) g[k] = *(const floatx4*)(gp + (k << 6));

        floatx4 sc[8];
#pragma unroll
        for (int k = 0; k < 8; ++k) {
            int col4 = (k << 6) + (tc << 2);
            sc[k] = *(const floatx4*)&lds[(rp << 11) + ((col4 << 2) ^ ((rp & 7) << 4))];
        }

        float sm = -3e38f;
#pragma unroll
        for (int k = 0; k < 8; ++k)
            sm = fmaxf(sm, fmaxf(fmaxf(sc[k].x, sc[k].y), fmaxf(sc[k].z, sc[k].w)));
#pragma unroll
        for (int off = 1; off < 16; off <<= 1) sm = fmaxf(sm, __shfl_xor(sm, off));

        float sum = 0.0f, z1 = -3e38f, z2 = -3e38f;
        int i1 = 0, i2 = 0;
#pragma unroll
        for (int k = 0; k < 8; ++k) {
            int col4 = (k << 6) + (tc << 2);
#pragma unroll
            for (int e = 0; e < 4; ++e) {
                float sv = sc[k][e];
                float z  = sv + g[k][e];
                int c = col4 + e;
                if (z > z1)      { z2 = z1; i2 = i1; z1 = z; i1 = c; }
                else if (z > z2) { z2 = z;  i2 = c; }
                float ev = __expf(sv - sm);
                sc[k][e] = ev;
                sum += ev;
            }
        }
#pragma unroll
        for (int off = 1; off < 16; off <<= 1) {
            sum += __shfl_xor(sum, off);
            float oz1 = __shfl_xor(z1, off);
            int   oi1 = __shfl_xor(i1, off);
            float oz2 = __shfl_xor(z2, off);
            int   oi2 = __shfl_xor(i2, off);
            if (better(oz1, oi1, z1, i1)) {
                float nz2; int ni2;
                if (better(z1, i1, oz2, oi2)) { nz2 = z1;  ni2 = i1; }
                else                          { nz2 = oz2; ni2 = oi2; }
                z1 = oz1; i1 = oi1; z2 = nz2; i2 = ni2;
            } else if (better(oz1, oi1, z2, i2)) { z2 = oz1; i2 = oi1; }
        }
        float inv = 1.0f / sum;
        float* dp = dist + (size_t)gr * 512 + (tc << 2);
#pragma unroll
        for (int k = 0; k < 8; ++k)
            *(floatx4*)(dp + (k << 6)) = sc[k] * inv;
        if (tc == 0) { fZ1[row] = z1; fI1[row] = i1; fZ2[row] = z2; fI2[row] = i2; }
        __syncthreads();
    }

    // ---- final: 16 rows per wave: near-tie fallback + out = E[idx] ----
    for (int j = 0; j < 16; ++j) {
        int row = (cg << 4) + j;
        int gr  = row0 + row;
        float Z1 = fZ1[row], Z2 = fZ2[row];
        int   I1 = fI1[row], I2 = fI2[row];
        int idxF = I1;
        if (Z1 - Z2 < GAP_T) {
            const float* xr  = X + (size_t)gr * 512 + (lane << 3);
            floatx4 x0 = *(const floatx4*)xr;
            floatx4 x1 = *(const floatx4*)(xr + 4);
            const float* e1p = E + (size_t)I1 * 512 + (lane << 3);
            const float* e2p = E + (size_t)I2 * 512 + (lane << 3);
            floatx4 a0 = *(const floatx4*)e1p, a1 = *(const floatx4*)(e1p + 4);
            floatx4 b0 = *(const floatx4*)e2p, b1 = *(const floatx4*)(e2p + 4);
            float d1 = x0.x*a0.x + x0.y*a0.y + x0.z*a0.z + x0.w*a0.w
                     + x1.x*a1.x + x1.y*a1.y + x1.z*a1.z + x1.w*a1.w;
            float d2 = x0.x*b0.x + x0.y*b0.y + x0.z*b0.z + x0.w*b0.w
                     + x1.x*b1.x + x1.y*b1.y + x1.z*b1.z + x1.w*b1.w;
#pragma unroll
            for (int off = 1; off < 64; off <<= 1) {
                d1 += __shfl_xor(d1, off);
                d2 += __shfl_xor(d2, off);
            }
            float z1p = d1 * SCALE + G[(size_t)gr * 512 + I1];
            float z2p = d2 * SCALE + G[(size_t)gr * 512 + I2];
            if (z2p > z1p || (z2p == z1p && I2 < I1)) idxF = I2;
        }
        const float* er = E + (size_t)idxF * 512 + (lane << 3);
        floatx4 e0 = *(const floatx4*)er;
        floatx4 e1 = *(const floatx4*)(er + 4);
        float* o = outp + (size_t)gr * 512 + (lane << 3);
        *(floatx4*)o = e0;
        *(floatx4*)(o + 4) = e1;
    }
}

extern "C" void kernel_launch(void* const* d_in, const int* in_sizes, int n_in,
                              void* d_out, int out_size, void* d_ws, size_t ws_size,
                              hipStream_t stream) {
    const float* X = (const float*)d_in[0];
    const float* E = (const float*)d_in[1];
    const float* G = (const float*)d_in[2];
    float* outp = (float*)d_out;
    float* dist = outp + (size_t)N_ROWS * 512;
    uint32_t* bImg = (uint32_t*)d_ws;          // 512 KiB

    prep_b<<<512, 256, 0, stream>>>(E, bImg);
    fused<<<N_ROWS / 64, 256, 0, stream>>>(X, E, G, bImg, outp, dist);
}

// Round 9
// 454.224 us; speedup vs baseline: 1.7111x; 1.7111x over previous
//
#include <hip/hip_runtime.h>
#include <stdint.h>

typedef __attribute__((ext_vector_type(4))) float  floatx4;
typedef __attribute__((ext_vector_type(4))) uint32_t uintx4;
typedef __bf16 bf16x8 __attribute__((ext_vector_type(8)));

#define N_ROWS 131072
#define SCALE 0.044194173824159216f   /* 1/sqrt(512) */
#define GAP_T 1e-4f                   /* bf16-z worst-case err ~3e-5; margin 3x */

/* bank-spread slot for 64B rows */
#define SLOT(c) ((((c) & 3) ^ (((c) >> 2) & 3)) << 4)

static __device__ __forceinline__ uint32_t bf16_rne(float x) {
    uint32_t u = __float_as_uint(x);
    return (u + 0x7FFFu + ((u >> 16) & 1u)) >> 16;
}

static __device__ __forceinline__ void gl_lds16(const void* g, void* l) {
    __builtin_amdgcn_global_load_lds(
        (const __attribute__((address_space(1))) void*)g,
        (__attribute__((address_space(3))) void*)l, 16, 0, 0);
}

static __device__ __forceinline__ bool better(float za, int ia, float zb, int ib) {
    return (za > zb) || (za == zb && ia < ib);
}

// ---------------------------------------------------------------------------
// Prep: E (f32 [512][512]) -> 16 pre-swizzled bf16 images of 32KB (k-chunks
// of 32, all 512 cols). LDS layout: byte(c, kb) = c*64 + (kb ^ SLOT(c)).
// ---------------------------------------------------------------------------
__global__ __launch_bounds__(256)
void prep_b(const float* __restrict__ E, uint32_t* __restrict__ bImg) {
    int w  = blockIdx.x * 256 + threadIdx.x;  // 0..131071 u32 words
    int ck = w >> 13;                          // 8192 words per 32KB image
    int o  = (w & 8191) << 2;                  // byte offset in image
    int c  = o >> 6;                           // code 0..511
    int kb = (o & 63) ^ SLOT(c);               // unswizzled k-byte
    int d  = (ck << 5) + (kb >> 1);
    float x0 = E[c * 512 + d];
    float x1 = E[c * 512 + d + 1];
    bImg[w] = bf16_rne(x0) | (bf16_rne(x1) << 16);
}

// ---------------------------------------------------------------------------
// Fused: block = 128 rows x 512 codes, 8 waves (2 rg x 4 cg), wave = 64x128
// (acc[4][8]).  LDS 48KB -> 3 blocks/CU.  K-loop: 16 chunks of k=32;
// single-buffered B (stage -> barrier -> 32 MFMA/wave -> barrier; cross-block
// TLP hides staging), double-buffered A.  Epilogue: 4 batches of 32 rows,
// each transposed in two 256-col halves (32KB buffer); row-contiguous
// softmax->dist, top2(s+g); final: near-tie exact-f32 fallback + out=E[idx].
// ---------------------------------------------------------------------------
__global__ __launch_bounds__(512, 3)
void fused(const float* __restrict__ X, const float* __restrict__ E,
           const float* __restrict__ G, const uint32_t* __restrict__ bImg,
           float* __restrict__ outp, float* __restrict__ dist) {
    __shared__ uint8_t lds[49152];
    // K: B @0 (32K), A par0 @32768 (8K), A par1 @40960 (8K)
    // Epi: transpose @0 (32K), stats @32768 (2K)
    const int t    = threadIdx.x;        // 0..511
    const int lane = t & 63;
    const int l15  = lane & 15;
    const int q    = lane >> 4;
    const int wv   = t >> 6;
    const int rg   = wv >> 2;
    const int cg   = wv & 3;
    const int row0 = blockIdx.x << 7;

    floatx4 acc[4][8];
#pragma unroll
    for (int mi = 0; mi < 4; ++mi)
#pragma unroll
        for (int nc = 0; nc < 8; ++nc) acc[mi][nc] = (floatx4)0.0f;

    // ---- staging geometry ----
    const int r_ld = t >> 2;             // A-stage row 0..127
    const int k8   = (t & 3) << 3;       // A-stage k elems (8)
    const float* xrow = X + (size_t)(row0 + r_ld) * 512 + k8;
    const int abyte = (r_ld << 6) + ((k8 << 1) ^ SLOT(r_ld));

#define STAGE_B(ck) {                                                        \
    const uint8_t* src_ = (const uint8_t*)bImg + ((ck) << 15);               \
    _Pragma("unroll")                                                        \
    for (int i_ = 0; i_ < 4; ++i_) {                                         \
        int off_ = (i_ << 13) + (t << 4);                                    \
        gl_lds16(src_ + off_, &lds[off_]);                                   \
    } }

#define WRITE_A(v0, v1, par) {                                               \
    uintx4 hv_;                                                              \
    hv_.x = bf16_rne((v0).x) | (bf16_rne((v0).y) << 16);                     \
    hv_.y = bf16_rne((v0).z) | (bf16_rne((v0).w) << 16);                     \
    hv_.z = bf16_rne((v1).x) | (bf16_rne((v1).y) << 16);                     \
    hv_.w = bf16_rne((v1).z) | (bf16_rne((v1).w) << 16);                     \
    *(uintx4*)&lds[32768 + ((par) << 13) + abyte] = hv_; }

#define COMPUTE(apar) {                                                      \
    const int aoff_ = 32768 + ((apar) << 13);                                \
    bf16x8 af_[4];                                                           \
    _Pragma("unroll")                                                        \
    for (int mi_ = 0; mi_ < 4; ++mi_) {                                      \
        int r_ = (rg << 6) + (mi_ << 4) + l15;                               \
        af_[mi_] = *(const bf16x8*)&lds[aoff_ + (r_ << 6) + ((q << 4) ^ SLOT(r_))]; \
    }                                                                        \
    _Pragma("unroll")                                                        \
    for (int nc_ = 0; nc_ < 8; ++nc_) {                                      \
        int c_ = (cg << 7) + (nc_ << 4) + l15;                               \
        bf16x8 b_ = *(const bf16x8*)&lds[(c_ << 6) + ((q << 4) ^ SLOT(c_))]; \
        _Pragma("unroll")                                                    \
        for (int mi_ = 0; mi_ < 4; ++mi_)                                    \
            acc[mi_][nc_] = __builtin_amdgcn_mfma_f32_16x16x32_bf16(af_[mi_], b_, acc[mi_][nc_], 0, 0, 0); \
    } }

    // ---- prologue: A(0) written; X regs hold chunk 1 ----
    floatx4 xa0 = *(const floatx4*)(xrow);
    floatx4 xa1 = *(const floatx4*)(xrow + 4);
    WRITE_A(xa0, xa1, 0);
    xa0 = *(const floatx4*)(xrow + 32);
    xa1 = *(const floatx4*)(xrow + 36);

    // ---- K loop: 16 chunks, single-buffered B ----
    for (int ck = 0; ck < 16; ++ck) {
        STAGE_B(ck);
        if (ck + 1 < 16) WRITE_A(xa0, xa1, (ck + 1) & 1);
        if (ck + 2 < 16) {
            xa0 = *(const floatx4*)(xrow + ((ck + 2) << 5));
            xa1 = *(const floatx4*)(xrow + ((ck + 2) << 5) + 4);
        }
        __syncthreads();              // B(ck) + A(ck+1) staged
        COMPUTE(ck & 1);
        __syncthreads();              // all reads done before next stage
    }

#pragma unroll
    for (int mi = 0; mi < 4; ++mi)
#pragma unroll
        for (int nc = 0; nc < 8; ++nc) acc[mi][nc] *= SCALE;

    // -------- epilogue: 4 batches of 32 rows, 2 col-halves each ----------
    float* fZ1 = (float*)(lds + 32768);          // [128]
    int*   fI1 = (int*)  (lds + 33280);
    float* fZ2 = (float*)(lds + 33792);
    int*   fI2 = (int*)  (lds + 34304);

    const int rp = t >> 4;    // 0..31 transposed row slot
    const int tc = t & 15;    // 16 threads per row

#pragma unroll
    for (int bt = 0; bt < 4; ++bt) {
        const int row = (bt << 5) + rp;          // local 0..127
        const int gr  = row0 + row;
        // hoist G loads: issue at batch start, consumed after transposes
        const float* gp = G + (size_t)gr * 512 + (tc << 2);
        floatx4 g[8];
#pragma unroll
        for (int k = 0; k < 8; ++k) g[k] = *(const floatx4*)(gp + (k << 6));

        floatx4 sc[8];
#pragma unroll
        for (int h = 0; h < 2; ++h) {
            // write rows of batch bt, cols half h (waves cg: cg>>1 == h)
            if (rg == (bt >> 1) && (cg >> 1) == h) {
#pragma unroll
                for (int m2 = 0; m2 < 2; ++m2) {
                    int mi = ((bt & 1) << 1) + m2;
#pragma unroll
                    for (int nc = 0; nc < 8; ++nc) {
                        int cp = ((cg & 1) << 7) + (nc << 4) + l15;  // 0..255
#pragma unroll
                        for (int p = 0; p < 4; ++p) {
                            int lr = (m2 << 4) + (q << 2) + p;       // 0..31
                            *(float*)&lds[(lr << 10) + ((cp << 2) ^ ((lr & 7) << 4))] = acc[mi][nc][p];
                        }
                    }
                }
            }
            __syncthreads();
#pragma unroll
            for (int kk = 0; kk < 4; ++kk) {
                int cp4 = (kk << 6) + (tc << 2);
                sc[(h << 2) + kk] = *(const floatx4*)&lds[(rp << 10) + ((cp4 << 2) ^ ((rp & 7) << 4))];
            }
            __syncthreads();
        }

        float sm = -3e38f;
#pragma unroll
        for (int k = 0; k < 8; ++k)
            sm = fmaxf(sm, fmaxf(fmaxf(sc[k].x, sc[k].y), fmaxf(sc[k].z, sc[k].w)));
#pragma unroll
        for (int off = 1; off < 16; off <<= 1) sm = fmaxf(sm, __shfl_xor(sm, off));

        float sum = 0.0f, z1 = -3e38f, z2 = -3e38f;
        int i1 = 0, i2 = 0;
#pragma unroll
        for (int k = 0; k < 8; ++k) {
            int col4 = (k << 6) + (tc << 2);
#pragma unroll
            for (int e = 0; e < 4; ++e) {
                float sv = sc[k][e];
                float z  = sv + g[k][e];
                int c = col4 + e;
                if (z > z1)      { z2 = z1; i2 = i1; z1 = z; i1 = c; }
                else if (z > z2) { z2 = z;  i2 = c; }
                float ev = __expf(sv - sm);
                sc[k][e] = ev;
                sum += ev;
            }
        }
#pragma unroll
        for (int off = 1; off < 16; off <<= 1) {
            sum += __shfl_xor(sum, off);
            float oz1 = __shfl_xor(z1, off);
            int   oi1 = __shfl_xor(i1, off);
            float oz2 = __shfl_xor(z2, off);
            int   oi2 = __shfl_xor(i2, off);
            if (better(oz1, oi1, z1, i1)) {
                float nz2; int ni2;
                if (better(z1, i1, oz2, oi2)) { nz2 = z1;  ni2 = i1; }
                else                          { nz2 = oz2; ni2 = oi2; }
                z1 = oz1; i1 = oi1; z2 = nz2; i2 = ni2;
            } else if (better(oz1, oi1, z2, i2)) { z2 = oz1; i2 = oi1; }
        }
        float inv = 1.0f / sum;
        float* dp = dist + (size_t)gr * 512 + (tc << 2);
#pragma unroll
        for (int k = 0; k < 8; ++k)
            *(floatx4*)(dp + (k << 6)) = sc[k] * inv;
        if (tc == 0) { fZ1[row] = z1; fI1[row] = i1; fZ2[row] = z2; fI2[row] = i2; }
        __syncthreads();
    }

    // ---- final: 16 rows per wave: near-tie fallback + out = E[idx] ----
    for (int j = 0; j < 16; ++j) {
        int row = (wv << 4) + j;
        int gr  = row0 + row;
        float Z1 = fZ1[row], Z2 = fZ2[row];
        int   I1 = fI1[row], I2 = fI2[row];
        int idxF = I1;
        if (Z1 - Z2 < GAP_T) {
            const float* xr  = X + (size_t)gr * 512 + (lane << 3);
            floatx4 x0 = *(const floatx4*)xr;
            floatx4 x1 = *(const floatx4*)(xr + 4);
            const float* e1p = E + (size_t)I1 * 512 + (lane << 3);
            const float* e2p = E + (size_t)I2 * 512 + (lane << 3);
            floatx4 a0 = *(const floatx4*)e1p, a1 = *(const floatx4*)(e1p + 4);
            floatx4 b0 = *(const floatx4*)e2p, b1 = *(const floatx4*)(e2p + 4);
            float d1 = x0.x*a0.x + x0.y*a0.y + x0.z*a0.z + x0.w*a0.w
                     + x1.x*a1.x + x1.y*a1.y + x1.z*a1.z + x1.w*a1.w;
            float d2 = x0.x*b0.x + x0.y*b0.y + x0.z*b0.z + x0.w*b0.w
                     + x1.x*b1.x + x1.y*b1.y + x1.z*b1.z + x1.w*b1.w;
#pragma unroll
            for (int off = 1; off < 64; off <<= 1) {
                d1 += __shfl_xor(d1, off);
                d2 += __shfl_xor(d2, off);
            }
            float z1p = d1 * SCALE + G[(size_t)gr * 512 + I1];
            float z2p = d2 * SCALE + G[(size_t)gr * 512 + I2];
            if (z2p > z1p || (z2p == z1p && I2 < I1)) idxF = I2;
        }
        const float* er = E + (size_t)idxF * 512 + (lane << 3);
        floatx4 e0 = *(const floatx4*)er;
        floatx4 e1 = *(const floatx4*)(er + 4);
        float* o = outp + (size_t)gr * 512 + (lane << 3);
        *(floatx4*)o = e0;
        *(floatx4*)(o + 4) = e1;
    }
}

extern "C" void kernel_launch(void* const* d_in, const int* in_sizes, int n_in,
                              void* d_out, int out_size, void* d_ws, size_t ws_size,
                              hipStream_t stream) {
    const float* X = (const float*)d_in[0];
    const float* E = (const float*)d_in[1];
    const float* G = (const float*)d_in[2];
    float* outp = (float*)d_out;
    float* dist = outp + (size_t)N_ROWS * 512;
    uint32_t* bImg = (uint32_t*)d_ws;          // 512 KiB

    prep_b<<<512, 256, 0, stream>>>(E, bImg);
    fused<<<N_ROWS / 128, 512, 0, stream>>>(X, E, G, bImg, outp, dist);
}

// Round 10
// 323.834 us; speedup vs baseline: 2.4000x; 1.4026x over previous
//
#include <hip/hip_runtime.h>
#include <stdint.h>

typedef __attribute__((ext_vector_type(4))) float  floatx4;
typedef __attribute__((ext_vector_type(4))) uint32_t uintx4;
typedef __bf16 bf16x8 __attribute__((ext_vector_type(8)));

#define N_ROWS 131072
#define SCALE 0.044194173824159216f   /* 1/sqrt(512) */
#define GAP_T 1e-4f                   /* bf16-z worst-case err ~3e-5; margin 3x */

/* bank-spread slot for 64B rows: rows r..r+15 hit each 16B bank-group 2-way */
#define SLOT(c) ((((c) & 3) ^ (((c) >> 2) & 3)) << 4)

static __device__ __forceinline__ uint32_t bf16_rne(float x) {
    uint32_t u = __float_as_uint(x);
    return (u + 0x7FFFu + ((u >> 16) & 1u)) >> 16;
}

static __device__ __forceinline__ void gl_lds16(const void* g, void* l) {
    __builtin_amdgcn_global_load_lds(
        (const __attribute__((address_space(1))) void*)g,
        (__attribute__((address_space(3))) void*)l, 16, 0, 0);
}

static __device__ __forceinline__ bool better(float za, int ia, float zb, int ib) {
    return (za > zb) || (za == zb && ia < ib);
}

// ---------------------------------------------------------------------------
// Prep: E (f32 [512][512]) -> 16 pre-swizzled bf16 images of 32KB (k-chunks
// of 32). LDS layout: byte(c, kb) = c*64 + (kb ^ SLOT(c)), kb = 2*(k%32).
// ---------------------------------------------------------------------------
__global__ __launch_bounds__(256)
void prep_b(const float* __restrict__ E, uint32_t* __restrict__ bImg) {
    int w  = blockIdx.x * 256 + threadIdx.x;  // 0..131071 u32 words
    int ck = w >> 13;                          // 8192 words per 32KB image
    int o  = (w & 8191) << 2;                  // byte offset in image
    int c  = o >> 6;                           // code 0..511
    int kb = (o & 63) ^ SLOT(c);               // unswizzled k-byte
    int d  = (ck << 5) + (kb >> 1);
    float x0 = E[c * 512 + d];
    float x1 = E[c * 512 + d + 1];
    bImg[w] = bf16_rne(x0) | (bf16_rne(x1) << 16);
}

// ---------------------------------------------------------------------------
// Fused (R6 structure, 255us): block = 128 rows x 512 codes, 8 waves
// (2 rg x 4 cg), wave = 64x128 (acc[4][8]).  2-phase double-buffered K-loop
// (16 steps of k=32).  Epilogue: 4 quarters of 32 rows LDS-transposed to
// row-contiguous; softmax->dist, top2(s+g); NEW: common-path out = E[i1]
// stored in-batch (reuses dead sc regs); rare near-tie rows fixed in a tiny
// flagged-only final pass (straight-through val == 1.0).
// ---------------------------------------------------------------------------
__global__ __launch_bounds__(512, 2)
void fused(const float* __restrict__ X, const float* __restrict__ E,
           const float* __restrict__ G, const uint32_t* __restrict__ bImg,
           float* __restrict__ outp, float* __restrict__ dist) {
    __shared__ uint8_t lds[81920];
    // K: B buf0 @0 (32K), B buf1 @32768, A buf0 @65536 (8K), A buf1 @73728
    // Epi: score quarter @0 (64K), stats @65536
    const int t    = threadIdx.x;
    const int lane = t & 63;
    const int l15  = lane & 15;
    const int q    = lane >> 4;
    const int wv   = t >> 6;
    const int rg   = wv >> 2;
    const int cg   = wv & 3;
    const int row0 = blockIdx.x << 7;

    floatx4 acc[4][8];
#pragma unroll
    for (int mi = 0; mi < 4; ++mi)
#pragma unroll
        for (int nc = 0; nc < 8; ++nc) acc[mi][nc] = (floatx4)0.0f;

    // ---- staging geometry ----
    const int r_ld = t >> 2;                 // A-stage row 0..127
    const int k8   = (t & 3) << 3;           // A-stage k elems (8)
    const float* xrow = X + (size_t)(row0 + r_ld) * 512 + k8;
    const int abyte = (r_ld << 6) + ((k8 << 1) ^ SLOT(r_ld));

#define STAGE_B(ck, par) {                                                   \
    const uint8_t* img_ = (const uint8_t*)bImg + ((ck) << 15);               \
    _Pragma("unroll")                                                        \
    for (int i_ = 0; i_ < 4; ++i_) {                                         \
        int off_ = (i_ << 13) + (t << 4);                                    \
        gl_lds16(img_ + off_, &lds[((par) << 15) + off_]);                   \
    } }

#define WRITE_A(v0, v1, par) {                                               \
    uintx4 hv_;                                                              \
    hv_.x = bf16_rne((v0).x) | (bf16_rne((v0).y) << 16);                     \
    hv_.y = bf16_rne((v0).z) | (bf16_rne((v0).w) << 16);                     \
    hv_.z = bf16_rne((v1).x) | (bf16_rne((v1).y) << 16);                     \
    hv_.w = bf16_rne((v1).z) | (bf16_rne((v1).w) << 16);                     \
    *(uintx4*)&lds[65536 + ((par) << 13) + abyte] = hv_; }

#define COMPUTE(par) {                                                       \
    const int boff_ = (par) << 15;                                           \
    const int aoff_ = 65536 + ((par) << 13);                                 \
    bf16x8 af_[4];                                                           \
    _Pragma("unroll")                                                        \
    for (int mi_ = 0; mi_ < 4; ++mi_) {                                      \
        int r_ = (rg << 6) + (mi_ << 4) + l15;                               \
        af_[mi_] = *(const bf16x8*)&lds[aoff_ + (r_ << 6) + ((q << 4) ^ SLOT(r_))]; \
    }                                                                        \
    _Pragma("unroll")                                                        \
    for (int nc_ = 0; nc_ < 8; ++nc_) {                                      \
        int c_ = (cg << 7) + (nc_ << 4) + l15;                               \
        bf16x8 b_ = *(const bf16x8*)&lds[boff_ + (c_ << 6) + ((q << 4) ^ SLOT(c_))]; \
        _Pragma("unroll")                                                    \
        for (int mi_ = 0; mi_ < 4; ++mi_)                                    \
            acc[mi_][nc_] = __builtin_amdgcn_mfma_f32_16x16x32_bf16(af_[mi_], b_, acc[mi_][nc_], 0, 0, 0); \
    } }

    // ---- prologue ----
    floatx4 xa0 = *(const floatx4*)(xrow);
    floatx4 xa1 = *(const floatx4*)(xrow + 4);
    STAGE_B(0, 0);
    WRITE_A(xa0, xa1, 0);
    floatx4 xb0 = *(const floatx4*)(xrow + 32);
    floatx4 xb1 = *(const floatx4*)(xrow + 36);
    __syncthreads();

    // ---- 2-phase pipeline, 16 steps ----
    for (int ck = 0; ck < 16; ck += 2) {
        if (ck + 1 < 16) { STAGE_B(ck + 1, 1); WRITE_A(xb0, xb1, 1); }
        if (ck + 2 < 16) {
            xa0 = *(const floatx4*)(xrow + ((ck + 2) << 5));
            xa1 = *(const floatx4*)(xrow + ((ck + 2) << 5) + 4);
        }
        COMPUTE(0);
        __syncthreads();
        if (ck + 2 < 16) { STAGE_B(ck + 2, 0); WRITE_A(xa0, xa1, 0); }
        if (ck + 3 < 16) {
            xb0 = *(const floatx4*)(xrow + ((ck + 3) << 5));
            xb1 = *(const floatx4*)(xrow + ((ck + 3) << 5) + 4);
        }
        COMPUTE(1);
        __syncthreads();
    }

#pragma unroll
    for (int mi = 0; mi < 4; ++mi)
#pragma unroll
        for (int nc = 0; nc < 8; ++nc) acc[mi][nc] *= SCALE;

    // -------- epilogue: 4 quarters of 32 rows ----------
    float* fZ1 = (float*)(lds + 65536);          // [128]
    int*   fI1 = (int*)  (lds + 65536 + 512);
    float* fZ2 = (float*)(lds + 65536 + 1024);
    int*   fI2 = (int*)  (lds + 65536 + 1536);

    const int rp = t >> 4;    // 0..31 transposed row slot
    const int tc = t & 15;    // 16 threads per row

#pragma unroll
    for (int Q = 0; Q < 4; ++Q) {
        if (rg == (Q >> 1)) {
#pragma unroll
            for (int m2 = 0; m2 < 2; ++m2) {
                int mi = ((Q & 1) << 1) + m2;
#pragma unroll
                for (int nc = 0; nc < 8; ++nc) {
                    int col = (cg << 7) + (nc << 4) + l15;
#pragma unroll
                    for (int p = 0; p < 4; ++p) {
                        int lr = (m2 << 4) + (q << 2) + p;   // 0..31
                        *(float*)&lds[(lr << 11) + ((col << 2) ^ ((lr & 7) << 4))] = acc[mi][nc][p];
                    }
                }
            }
        }
        __syncthreads();

        const int row = (Q << 5) + rp;           // local 0..127
        const int gr  = row0 + row;

        // issue G loads FIRST (latency hides under sm phase)
        const float* gp = G + (size_t)gr * 512 + (tc << 2);
        floatx4 g[8];
#pragma unroll
        for (int k = 0; k < 8; ++k) g[k] = *(const floatx4*)(gp + (k << 6));

        floatx4 sc[8];
#pragma unroll
        for (int k = 0; k < 8; ++k) {
            int col4 = (k << 6) + (tc << 2);
            sc[k] = *(const floatx4*)&lds[(rp << 11) + ((col4 << 2) ^ ((rp & 7) << 4))];
        }

        float sm = -3e38f;
#pragma unroll
        for (int k = 0; k < 8; ++k)
            sm = fmaxf(sm, fmaxf(fmaxf(sc[k].x, sc[k].y), fmaxf(sc[k].z, sc[k].w)));
#pragma unroll
        for (int off = 1; off < 16; off <<= 1) sm = fmaxf(sm, __shfl_xor(sm, off));

        float sum = 0.0f, z1 = -3e38f, z2 = -3e38f;
        int i1 = 0, i2 = 0;
#pragma unroll
        for (int k = 0; k < 8; ++k) {
            int col4 = (k << 6) + (tc << 2);
#pragma unroll
            for (int e = 0; e < 4; ++e) {
                float sv = sc[k][e];
                float z  = sv + g[k][e];
                int c = col4 + e;
                if (z > z1)      { z2 = z1; i2 = i1; z1 = z; i1 = c; }
                else if (z > z2) { z2 = z;  i2 = c; }
                float ev = __expf(sv - sm);
                sc[k][e] = ev;
                sum += ev;
            }
        }
#pragma unroll
        for (int off = 1; off < 16; off <<= 1) {
            sum += __shfl_xor(sum, off);
            float oz1 = __shfl_xor(z1, off);
            int   oi1 = __shfl_xor(i1, off);
            float oz2 = __shfl_xor(z2, off);
            int   oi2 = __shfl_xor(i2, off);
            if (better(oz1, oi1, z1, i1)) {
                float nz2; int ni2;
                if (better(z1, i1, oz2, oi2)) { nz2 = z1;  ni2 = i1; }
                else                          { nz2 = oz2; ni2 = oi2; }
                z1 = oz1; i1 = oi1; z2 = nz2; i2 = ni2;
            } else if (better(oz1, oi1, z2, i2)) { z2 = oz1; i2 = oi1; }
        }
        float inv = 1.0f / sum;
        float* dp = dist + (size_t)gr * 512 + (tc << 2);
#pragma unroll
        for (int k = 0; k < 8; ++k)
            *(floatx4*)(dp + (k << 6)) = sc[k] * inv;
        if (tc == 0) { fZ1[row] = z1; fI1[row] = i1; fZ2[row] = z2; fI2[row] = i2; }

        // ---- NEW: common-path out = E[i1], in-batch (sc regs are dead) ----
        {
            const float* er = E + (size_t)i1 * 512 + (tc << 5);
            float* op = outp + (size_t)gr * 512 + (tc << 5);
#pragma unroll
            for (int u = 0; u < 8; ++u)
                sc[u] = *(const floatx4*)(er + (u << 2));
#pragma unroll
            for (int u = 0; u < 8; ++u)
                *(floatx4*)(op + (u << 2)) = sc[u];
        }
        __syncthreads();
    }

    // ---- final: flagged rows only (near ties): exact-f32 fallback ----
    for (int j = 0; j < 16; ++j) {
        int row = (wv << 4) + j;
        float Z1 = fZ1[row], Z2 = fZ2[row];
        if (Z1 - Z2 >= GAP_T) continue;
        int gr  = row0 + row;
        int I1 = fI1[row], I2 = fI2[row];
        const float* xr  = X + (size_t)gr * 512 + (lane << 3);
        floatx4 x0 = *(const floatx4*)xr;
        floatx4 x1 = *(const floatx4*)(xr + 4);
        const float* e1p = E + (size_t)I1 * 512 + (lane << 3);
        const float* e2p = E + (size_t)I2 * 512 + (lane << 3);
        floatx4 a0 = *(const floatx4*)e1p, a1 = *(const floatx4*)(e1p + 4);
        floatx4 b0 = *(const floatx4*)e2p, b1 = *(const floatx4*)(e2p + 4);
        float d1 = x0.x*a0.x + x0.y*a0.y + x0.z*a0.z + x0.w*a0.w
                 + x1.x*a1.x + x1.y*a1.y + x1.z*a1.z + x1.w*a1.w;
        float d2 = x0.x*b0.x + x0.y*b0.y + x0.z*b0.z + x0.w*b0.w
                 + x1.x*b1.x + x1.y*b1.y + x1.z*b1.z + x1.w*b1.w;
#pragma unroll
        for (int off = 1; off < 64; off <<= 1) {
            d1 += __shfl_xor(d1, off);
            d2 += __shfl_xor(d2, off);
        }
        float z1p = d1 * SCALE + G[(size_t)gr * 512 + I1];
        float z2p = d2 * SCALE + G[(size_t)gr * 512 + I2];
        int idxF = (z2p > z1p || (z2p == z1p && I2 < I1)) ? I2 : I1;
        const float* er = E + (size_t)idxF * 512 + (lane << 3);
        floatx4 e0 = *(const floatx4*)er;
        floatx4 e1 = *(const floatx4*)(er + 4);
        float* o = outp + (size_t)gr * 512 + (lane << 3);
        *(floatx4*)o = e0;
        *(floatx4*)(o + 4) = e1;
    }
}

extern "C" void kernel_launch(void* const* d_in, const int* in_sizes, int n_in,
                              void* d_out, int out_size, void* d_ws, size_t ws_size,
                              hipStream_t stream) {
    const float* X = (const float*)d_in[0];
    const float* E = (const float*)d_in[1];
    const float* G = (const float*)d_in[2];
    float* outp = (float*)d_out;
    float* dist = outp + (size_t)N_ROWS * 512;
    uint32_t* bImg = (uint32_t*)d_ws;          // 512 KiB

    prep_b<<<512, 256, 0, stream>>>(E, bImg);
    fused<<<N_ROWS / 128, 512, 0, stream>>>(X, E, G, bImg, outp, dist);
}

// Round 11
// 302.213 us; speedup vs baseline: 2.5717x; 1.0715x over previous
//
#include <hip/hip_runtime.h>
#include <stdint.h>

typedef __attribute__((ext_vector_type(4))) float  floatx4;
typedef __attribute__((ext_vector_type(4))) uint32_t uintx4;
typedef __bf16 bf16x8 __attribute__((ext_vector_type(8)));

#define N_ROWS 131072
#define SCALE 0.044194173824159216f   /* 1/sqrt(512) */
#define GAP_T 1e-4f                   /* bf16-z worst-case err ~3e-5; margin 3x */

/* bank-spread slot for 64B rows */
#define SLOT(c) ((((c) & 3) ^ (((c) >> 2) & 3)) << 4)

static __device__ __forceinline__ uint32_t bf16_rne(float x) {
    uint32_t u = __float_as_uint(x);
    return (u + 0x7FFFu + ((u >> 16) & 1u)) >> 16;
}

static __device__ __forceinline__ void gl_lds16(const void* g, void* l) {
    __builtin_amdgcn_global_load_lds(
        (const __attribute__((address_space(1))) void*)g,
        (__attribute__((address_space(3))) void*)l, 16, 0, 0);
}

static __device__ __forceinline__ bool better(float za, int ia, float zb, int ib) {
    return (za > zb) || (za == zb && ia < ib);
}

// ---------------------------------------------------------------------------
// Prep: E (f32 [512][512]) -> 32 pre-swizzled bf16 images of 16KB.
// Image img = ck*2 + h: k-chunk ck (32 k's), column half h (256 codes).
// Layout: byte(c', kb) = c'*64 + (kb ^ SLOT(c')), c' = col within half.
// ---------------------------------------------------------------------------
__global__ __launch_bounds__(256)
void prep_b(const float* __restrict__ E, uint32_t* __restrict__ bImg) {
    int w   = blockIdx.x * 256 + threadIdx.x;  // 0..131071 u32 words
    int img = w >> 12;                          // 4096 words per 16KB image
    int o   = (w & 4095) << 2;                  // byte offset in image
    int cp  = o >> 6;                           // col-in-half 0..255
    int kb  = (o & 63) ^ SLOT(cp);              // unswizzled k-byte
    int d   = ((img >> 1) << 5) + (kb >> 1);
    int col = ((img & 1) << 8) + cp;
    float x0 = E[col * 512 + d];
    float x1 = E[col * 512 + d + 1];
    bImg[w] = bf16_rne(x0) | (bf16_rne(x1) << 16);
}

// ---------------------------------------------------------------------------
// Fused: block = 128 rows x 512 codes, 8 waves (2 rg x 4 cg), wave = 64x128.
// LDS 48KB -> 2 blocks/CU.  K-loop: 32 stages = 16 k-chunks x 2 col-halves;
// B dbuf 2x16KB stage-ahead (R6 overlap structure), A dbuf 2x8KB (frags
// reused across halves).  Epilogue: 4 batches of 32 rows, transposed per
// 256-col half (32KB buffer); softmax->dist, top2(s+g); final pass:
// near-tie exact-f32 fallback + out = E[idx] (straight-through val == 1.0).
// ---------------------------------------------------------------------------
__global__ __launch_bounds__(512, 2)
void fused(const float* __restrict__ X, const float* __restrict__ E,
           const float* __restrict__ G, const uint32_t* __restrict__ bImg,
           float* __restrict__ outp, float* __restrict__ dist) {
    __shared__ uint8_t lds[49152];
    // K: B buf0 @0 (16K), B buf1 @16384, A par0 @32768 (8K), A par1 @40960
    // Epi: transpose @0 (32K), stats @32768
    const int t    = threadIdx.x;        // 0..511
    const int lane = t & 63;
    const int l15  = lane & 15;
    const int q    = lane >> 4;
    const int wv   = t >> 6;
    const int rg   = wv >> 2;
    const int cg   = wv & 3;
    const int row0 = blockIdx.x << 7;

    floatx4 acc[4][8];                   // [mi][(h<<2)+nc]
#pragma unroll
    for (int mi = 0; mi < 4; ++mi)
#pragma unroll
        for (int nc = 0; nc < 8; ++nc) acc[mi][nc] = (floatx4)0.0f;

    // ---- staging geometry ----
    const int r_ld = t >> 2;             // A-stage row 0..127
    const int k8   = (t & 3) << 3;       // A-stage k elems (8)
    const float* xrow = X + (size_t)(row0 + r_ld) * 512 + k8;
    const int abyte = (r_ld << 6) + ((k8 << 1) ^ SLOT(r_ld));

#define STAGE_B(img, par) {                                                  \
    const uint8_t* src_ = (const uint8_t*)bImg + ((img) << 14);              \
    _Pragma("unroll")                                                        \
    for (int i_ = 0; i_ < 2; ++i_) {                                         \
        int off_ = (i_ << 13) + (t << 4);                                    \
        gl_lds16(src_ + off_, &lds[((par) << 14) + off_]);                   \
    } }

#define WRITE_A(v0, v1, par) {                                               \
    uintx4 hv_;                                                              \
    hv_.x = bf16_rne((v0).x) | (bf16_rne((v0).y) << 16);                     \
    hv_.y = bf16_rne((v0).z) | (bf16_rne((v0).w) << 16);                     \
    hv_.z = bf16_rne((v1).x) | (bf16_rne((v1).y) << 16);                     \
    hv_.w = bf16_rne((v1).z) | (bf16_rne((v1).w) << 16);                     \
    *(uintx4*)&lds[32768 + ((par) << 13) + abyte] = hv_; }

    // hh/bpar literal 0/1; apar runtime (addr only); reload literal
#define COMPUTE(hh, apar, reload) {                                          \
    const int aoff_ = 32768 + ((apar) << 13);                                \
    if (reload) {                                                            \
        _Pragma("unroll")                                                    \
        for (int mi_ = 0; mi_ < 4; ++mi_) {                                  \
            int r_ = (rg << 6) + (mi_ << 4) + l15;                           \
            af[mi_] = *(const bf16x8*)&lds[aoff_ + (r_ << 6) + ((q << 4) ^ SLOT(r_))]; \
        }                                                                    \
    }                                                                        \
    _Pragma("unroll")                                                        \
    for (int nc_ = 0; nc_ < 4; ++nc_) {                                      \
        int cp_ = (cg << 6) + (nc_ << 4) + l15;                              \
        bf16x8 b_ = *(const bf16x8*)&lds[((hh) << 14) + (cp_ << 6) + ((q << 4) ^ SLOT(cp_))]; \
        _Pragma("unroll")                                                    \
        for (int mi_ = 0; mi_ < 4; ++mi_)                                    \
            acc[mi_][((hh) << 2) + nc_] = __builtin_amdgcn_mfma_f32_16x16x32_bf16(af[mi_], b_, acc[mi_][((hh) << 2) + nc_], 0, 0, 0); \
    } }

    // ---- prologue: (ck0,h0)->buf0; A(ck0); X regs hold ck1 ----
    floatx4 xa0 = *(const floatx4*)(xrow);
    floatx4 xa1 = *(const floatx4*)(xrow + 4);
    STAGE_B(0, 0);
    WRITE_A(xa0, xa1, 0);
    xa0 = *(const floatx4*)(xrow + 32);
    xa1 = *(const floatx4*)(xrow + 36);
    __syncthreads();

    bf16x8 af[4];
    for (int ck = 0; ck < 16; ++ck) {
        // stage (ck,h1)->buf1; compute (ck,h0) from buf0 (A-frag reload)
        STAGE_B((ck << 1) + 1, 1);
        COMPUTE(0, ck & 1, 1);
        __syncthreads();
        // stage (ck+1,h0)->buf0 + A(ck+1); X(ck+2); compute (ck,h1) from buf1
        if (ck + 1 < 16) {
            STAGE_B((ck + 1) << 1, 0);
            WRITE_A(xa0, xa1, (ck + 1) & 1);
        }
        if (ck + 2 < 16) {
            xa0 = *(const floatx4*)(xrow + ((ck + 2) << 5));
            xa1 = *(const floatx4*)(xrow + ((ck + 2) << 5) + 4);
        }
        COMPUTE(1, ck & 1, 0);
        __syncthreads();
    }

#pragma unroll
    for (int mi = 0; mi < 4; ++mi)
#pragma unroll
        for (int nc = 0; nc < 8; ++nc) acc[mi][nc] *= SCALE;

    // -------- epilogue: 4 batches of 32 rows, 2 col-halves each ----------
    float* fZ1 = (float*)(lds + 32768);          // [128]
    int*   fI1 = (int*)  (lds + 33280);
    float* fZ2 = (float*)(lds + 33792);
    int*   fI2 = (int*)  (lds + 34304);

    const int rp = t >> 4;    // 0..31 transposed row slot
    const int tc = t & 15;    // 16 threads per row

#pragma unroll
    for (int bt = 0; bt < 4; ++bt) {
        const int row = (bt << 5) + rp;          // local 0..127
        const int gr  = row0 + row;
        // hoist G loads: issued before transposes, consumed after
        const float* gp = G + (size_t)gr * 512 + (tc << 2);
        floatx4 g[8];
#pragma unroll
        for (int k = 0; k < 8; ++k) g[k] = *(const floatx4*)(gp + (k << 6));

        floatx4 sc[8];
#pragma unroll
        for (int h = 0; h < 2; ++h) {
            // writers: waves with rg == bt>>1 (their mi pair covers batch rows)
            if (rg == (bt >> 1)) {
#pragma unroll
                for (int m2 = 0; m2 < 2; ++m2) {
                    int mi = ((bt & 1) << 1) + m2;
#pragma unroll
                    for (int nc = 0; nc < 4; ++nc) {
                        int cp = (cg << 6) + (nc << 4) + l15;        // 0..255
#pragma unroll
                        for (int p = 0; p < 4; ++p) {
                            int lr = (m2 << 4) + (q << 2) + p;       // 0..31
                            *(float*)&lds[(lr << 10) + ((cp << 2) ^ ((lr & 7) << 4))] = acc[mi][(h << 2) + nc][p];
                        }
                    }
                }
            }
            __syncthreads();
#pragma unroll
            for (int kk = 0; kk < 4; ++kk) {
                int cp4 = (kk << 6) + (tc << 2);
                sc[(h << 2) + kk] = *(const floatx4*)&lds[(rp << 10) + ((cp4 << 2) ^ ((rp & 7) << 4))];
            }
            __syncthreads();
        }
        // sc[(h<<2)+kk] holds cols (h<<8)+(kk<<6)+(tc<<2) .. +4

        float sm = -3e38f;
#pragma unroll
        for (int k = 0; k < 8; ++k)
            sm = fmaxf(sm, fmaxf(fmaxf(sc[k].x, sc[k].y), fmaxf(sc[k].z, sc[k].w)));
#pragma unroll
        for (int off = 1; off < 16; off <<= 1) sm = fmaxf(sm, __shfl_xor(sm, off));

        float sum = 0.0f, z1 = -3e38f, z2 = -3e38f;
        int i1 = 0, i2 = 0;
#pragma unroll
        for (int h = 0; h < 2; ++h)
#pragma unroll
            for (int kk = 0; kk < 4; ++kk) {
                int col4 = (h << 8) + (kk << 6) + (tc << 2);
                int k = (h << 2) + kk;
#pragma unroll
                for (int e = 0; e < 4; ++e) {
                    float sv = sc[k][e];
                    float z  = sv + g[k][e];
                    int c = col4 + e;
                    if (z > z1)      { z2 = z1; i2 = i1; z1 = z; i1 = c; }
                    else if (z > z2) { z2 = z;  i2 = c; }
                    float ev = __expf(sv - sm);
                    sc[k][e] = ev;
                    sum += ev;
                }
            }
#pragma unroll
        for (int off = 1; off < 16; off <<= 1) {
            sum += __shfl_xor(sum, off);
            float oz1 = __shfl_xor(z1, off);
            int   oi1 = __shfl_xor(i1, off);
            float oz2 = __shfl_xor(z2, off);
            int   oi2 = __shfl_xor(i2, off);
            if (better(oz1, oi1, z1, i1)) {
                float nz2; int ni2;
                if (better(z1, i1, oz2, oi2)) { nz2 = z1;  ni2 = i1; }
                else                          { nz2 = oz2; ni2 = oi2; }
                z1 = oz1; i1 = oi1; z2 = nz2; i2 = ni2;
            } else if (better(oz1, oi1, z2, i2)) { z2 = oz1; i2 = oi1; }
        }
        float inv = 1.0f / sum;
        float* dp = dist + (size_t)gr * 512;
#pragma unroll
        for (int h = 0; h < 2; ++h)
#pragma unroll
            for (int kk = 0; kk < 4; ++kk)
                *(floatx4*)(dp + (h << 8) + (kk << 6) + (tc << 2)) = sc[(h << 2) + kk] * inv;
        if (tc == 0) { fZ1[row] = z1; fI1[row] = i1; fZ2[row] = z2; fI2[row] = i2; }
        __syncthreads();
    }

    // ---- final: 16 rows per wave: near-tie fallback + out = E[idx] ----
    for (int j = 0; j < 16; ++j) {
        int row = (wv << 4) + j;
        int gr  = row0 + row;
        float Z1 = fZ1[row], Z2 = fZ2[row];
        int   I1 = fI1[row], I2 = fI2[row];
        int idxF = I1;
        if (Z1 - Z2 < GAP_T) {
            const float* xr  = X + (size_t)gr * 512 + (lane << 3);
            floatx4 x0 = *(const floatx4*)xr;
            floatx4 x1 = *(const floatx4*)(xr + 4);
            const float* e1p = E + (size_t)I1 * 512 + (lane << 3);
            const float* e2p = E + (size_t)I2 * 512 + (lane << 3);
            floatx4 a0 = *(const floatx4*)e1p, a1 = *(const floatx4*)(e1p + 4);
            floatx4 b0 = *(const floatx4*)e2p, b1 = *(const floatx4*)(e2p + 4);
            float d1 = x0.x*a0.x + x0.y*a0.y + x0.z*a0.z + x0.w*a0.w
                     + x1.x*a1.x + x1.y*a1.y + x1.z*a1.z + x1.w*a1.w;
            float d2 = x0.x*b0.x + x0.y*b0.y + x0.z*b0.z + x0.w*b0.w
                     + x1.x*b1.x + x1.y*b1.y + x1.z*b1.z + x1.w*b1.w;
#pragma unroll
            for (int off = 1; off < 64; off <<= 1) {
                d1 += __shfl_xor(d1, off);
                d2 += __shfl_xor(d2, off);
            }
            float z1p = d1 * SCALE + G[(size_t)gr * 512 + I1];
            float z2p = d2 * SCALE + G[(size_t)gr * 512 + I2];
            if (z2p > z1p || (z2p == z1p && I2 < I1)) idxF = I2;
        }
        const float* er = E + (size_t)idxF * 512 + (lane << 3);
        floatx4 e0 = *(const floatx4*)er;
        floatx4 e1 = *(const floatx4*)(er + 4);
        float* o = outp + (size_t)gr * 512 + (lane << 3);
        *(floatx4*)o = e0;
        *(floatx4*)(o + 4) = e1;
    }
}

extern "C" void kernel_launch(void* const* d_in, const int* in_sizes, int n_in,
                              void* d_out, int out_size, void* d_ws, size_t ws_size,
                              hipStream_t stream) {
    const float* X = (const float*)d_in[0];
    const float* E = (const float*)d_in[1];
    const float* G = (const float*)d_in[2];
    float* outp = (float*)d_out;
    float* dist = outp + (size_t)N_ROWS * 512;
    uint32_t* bImg = (uint32_t*)d_ws;          // 512 KiB

    prep_b<<<512, 256, 0, stream>>>(E, bImg);
    fused<<<N_ROWS / 128, 512, 0, stream>>>(X, E, G, bImg, outp, dist);
}

// Round 12
// 259.913 us; speedup vs baseline: 2.9903x; 1.1627x over previous
//
#include <hip/hip_runtime.h>
#include <stdint.h>

typedef __attribute__((ext_vector_type(4))) float  floatx4;
typedef __attribute__((ext_vector_type(4))) uint32_t uintx4;
typedef __bf16 bf16x8 __attribute__((ext_vector_type(8)));

#define N_ROWS 131072
#define SCALE 0.044194173824159216f   /* 1/sqrt(512) */
#define GAP_T 1e-4f                   /* bf16-z worst-case err ~3e-5; margin 3x */

/* bank-spread slot for 64B rows: rows r..r+15 hit each 16B bank-group 2-way */
#define SLOT(c) ((((c) & 3) ^ (((c) >> 2) & 3)) << 4)

static __device__ __forceinline__ uint32_t bf16_rne(float x) {
    uint32_t u = __float_as_uint(x);
    return (u + 0x7FFFu + ((u >> 16) & 1u)) >> 16;
}

static __device__ __forceinline__ void gl_lds16(const void* g, void* l) {
    __builtin_amdgcn_global_load_lds(
        (const __attribute__((address_space(1))) void*)g,
        (__attribute__((address_space(3))) void*)l, 16, 0, 0);
}

static __device__ __forceinline__ bool better(float za, int ia, float zb, int ib) {
    return (za > zb) || (za == zb && ia < ib);
}

// ---------------------------------------------------------------------------
// Prep: E (f32 [512][512]) -> 16 pre-swizzled bf16 images of 32KB (k-chunks
// of 32). LDS layout: byte(c, kb) = c*64 + (kb ^ SLOT(c)), kb = 2*(k%32).
// ---------------------------------------------------------------------------
__global__ __launch_bounds__(256)
void prep_b(const float* __restrict__ E, uint32_t* __restrict__ bImg) {
    int w  = blockIdx.x * 256 + threadIdx.x;  // 0..131071 u32 words
    int ck = w >> 13;                          // 8192 words per 32KB image
    int o  = (w & 8191) << 2;                  // byte offset in image
    int c  = o >> 6;                           // code 0..511
    int kb = (o & 63) ^ SLOT(c);               // unswizzled k-byte
    int d  = (ck << 5) + (kb >> 1);
    float x0 = E[c * 512 + d];
    float x1 = E[c * 512 + d + 1];
    bImg[w] = bf16_rne(x0) | (bf16_rne(x1) << 16);
}

// ---------------------------------------------------------------------------
// Fused: block = 128 rows x 512 codes, 8 waves (2 rg x 4 cg), wave = 64x128
// (acc[4][8]).  2-phase double-buffered K-loop (16 steps of k=32).
// Epilogue: 4 quarters of 32 rows LDS-transposed to row-contiguous; per row
// (16-thread group): early G issue, softmax->dist, top2(s+g); final pass:
// near-tie exact-f32 fallback + out = E[idx] (straight-through val == 1.0).
// NOTE: this exact code shape keeps arch-VGPR at 64 (acc in AGPRs) -> 2
// blocks/CU.  Restructures (R7/R9/R10/R11) all inflated VGPR to ~128 and
// halved occupancy; do not modify COMPUTE/epilogue register lifetimes.
// ---------------------------------------------------------------------------
__global__ __launch_bounds__(512, 2)
void fused(const float* __restrict__ X, const float* __restrict__ E,
           const float* __restrict__ G, const uint32_t* __restrict__ bImg,
           float* __restrict__ outp, float* __restrict__ dist) {
    __shared__ uint8_t lds[81920];
    // K: B buf0 @0 (32K), B buf1 @32768, A buf0 @65536 (8K), A buf1 @73728
    // Epi: score quarter @0 (64K), stats @65536
    const int t    = threadIdx.x;
    const int lane = t & 63;
    const int l15  = lane & 15;
    const int q    = lane >> 4;
    const int wv   = t >> 6;
    const int rg   = wv >> 2;
    const int cg   = wv & 3;
    const int row0 = blockIdx.x << 7;

    floatx4 acc[4][8];
#pragma unroll
    for (int mi = 0; mi < 4; ++mi)
#pragma unroll
        for (int nc = 0; nc < 8; ++nc) acc[mi][nc] = (floatx4)0.0f;

    // ---- staging geometry ----
    const int r_ld = t >> 2;                 // A-stage row 0..127
    const int k8   = (t & 3) << 3;           // A-stage k elems (8)
    const float* xrow = X + (size_t)(row0 + r_ld) * 512 + k8;
    const int abyte = (r_ld << 6) + ((k8 << 1) ^ SLOT(r_ld));

#define STAGE_B(ck, par) {                                                   \
    const uint8_t* img_ = (const uint8_t*)bImg + ((ck) << 15);               \
    _Pragma("unroll")                                                        \
    for (int i_ = 0; i_ < 4; ++i_) {                                         \
        int off_ = (i_ << 13) + (t << 4);                                    \
        gl_lds16(img_ + off_, &lds[((par) << 15) + off_]);                   \
    } }

#define WRITE_A(v0, v1, par) {                                               \
    uintx4 hv_;                                                              \
    hv_.x = bf16_rne((v0).x) | (bf16_rne((v0).y) << 16);                     \
    hv_.y = bf16_rne((v0).z) | (bf16_rne((v0).w) << 16);                     \
    hv_.z = bf16_rne((v1).x) | (bf16_rne((v1).y) << 16);                     \
    hv_.w = bf16_rne((v1).z) | (bf16_rne((v1).w) << 16);                     \
    *(uintx4*)&lds[65536 + ((par) << 13) + abyte] = hv_; }

#define COMPUTE(par) {                                                       \
    const int boff_ = (par) << 15;                                           \
    const int aoff_ = 65536 + ((par) << 13);                                 \
    bf16x8 af_[4];                                                           \
    _Pragma("unroll")                                                        \
    for (int mi_ = 0; mi_ < 4; ++mi_) {                                      \
        int r_ = (rg << 6) + (mi_ << 4) + l15;                               \
        af_[mi_] = *(const bf16x8*)&lds[aoff_ + (r_ << 6) + ((q << 4) ^ SLOT(r_))]; \
    }                                                                        \
    _Pragma("unroll")                                                        \
    for (int nc_ = 0; nc_ < 8; ++nc_) {                                      \
        int c_ = (cg << 7) + (nc_ << 4) + l15;                               \
        bf16x8 b_ = *(const bf16x8*)&lds[boff_ + (c_ << 6) + ((q << 4) ^ SLOT(c_))]; \
        _Pragma("unroll")                                                    \
        for (int mi_ = 0; mi_ < 4; ++mi_)                                    \
            acc[mi_][nc_] = __builtin_amdgcn_mfma_f32_16x16x32_bf16(af_[mi_], b_, acc[mi_][nc_], 0, 0, 0); \
    } }

    // ---- prologue ----
    floatx4 xa0 = *(const floatx4*)(xrow);
    floatx4 xa1 = *(const floatx4*)(xrow + 4);
    STAGE_B(0, 0);
    WRITE_A(xa0, xa1, 0);
    floatx4 xb0 = *(const floatx4*)(xrow + 32);
    floatx4 xb1 = *(const floatx4*)(xrow + 36);
    __syncthreads();

    // ---- 2-phase pipeline, 16 steps ----
    for (int ck = 0; ck < 16; ck += 2) {
        if (ck + 1 < 16) { STAGE_B(ck + 1, 1); WRITE_A(xb0, xb1, 1); }
        if (ck + 2 < 16) {
            xa0 = *(const floatx4*)(xrow + ((ck + 2) << 5));
            xa1 = *(const floatx4*)(xrow + ((ck + 2) << 5) + 4);
        }
        COMPUTE(0);
        __syncthreads();
        if (ck + 2 < 16) { STAGE_B(ck + 2, 0); WRITE_A(xa0, xa1, 0); }
        if (ck + 3 < 16) {
            xb0 = *(const floatx4*)(xrow + ((ck + 3) << 5));
            xb1 = *(const floatx4*)(xrow + ((ck + 3) << 5) + 4);
        }
        COMPUTE(1);
        __syncthreads();
    }

#pragma unroll
    for (int mi = 0; mi < 4; ++mi)
#pragma unroll
        for (int nc = 0; nc < 8; ++nc) acc[mi][nc] *= SCALE;

    // -------- epilogue: 4 quarters of 32 rows, everything fused ----------
    const int rp = t >> 4;    // 0..31 transposed row slot
    const int tc = t & 15;    // 16 threads per row

    float* fZ1 = (float*)(lds + 65536);          // [128]
    int*   fI1 = (int*)  (lds + 65536 + 512);
    float* fZ2 = (float*)(lds + 65536 + 1024);
    int*   fI2 = (int*)  (lds + 65536 + 1536);

#pragma unroll
    for (int Q = 0; Q < 4; ++Q) {
        if (rg == (Q >> 1)) {
#pragma unroll
            for (int m2 = 0; m2 < 2; ++m2) {
                int mi = ((Q & 1) << 1) + m2;
#pragma unroll
                for (int nc = 0; nc < 8; ++nc) {
                    int col = (cg << 7) + (nc << 4) + l15;
#pragma unroll
                    for (int p = 0; p < 4; ++p) {
                        int lr = (m2 << 4) + (q << 2) + p;   // 0..31
                        *(float*)&lds[(lr << 11) + ((col << 2) ^ ((lr & 7) << 4))] = acc[mi][nc][p];
                    }
                }
            }
        }
        __syncthreads();

        const int row = (Q << 5) + rp;           // local 0..127
        const int gr  = row0 + row;

        // issue G loads FIRST (latency hides under sm phase)
        const float* gp = G + (size_t)gr * 512 + (tc << 2);
        floatx4 g[8];
#pragma unroll
        for (int k = 0; k < 8; ++k) g[k] = *(const floatx4*)(gp + (k << 6));

        floatx4 sc[8];
#pragma unroll
        for (int k = 0; k < 8; ++k) {
            int col4 = (k << 6) + (tc << 2);
            sc[k] = *(const floatx4*)&lds[(rp << 11) + ((col4 << 2) ^ ((rp & 7) << 4))];
        }

        float sm = -3e38f;
#pragma unroll
        for (int k = 0; k < 8; ++k)
            sm = fmaxf(sm, fmaxf(fmaxf(sc[k].x, sc[k].y), fmaxf(sc[k].z, sc[k].w)));
#pragma unroll
        for (int off = 1; off < 16; off <<= 1) sm = fmaxf(sm, __shfl_xor(sm, off));

        float sum = 0.0f, z1 = -3e38f, z2 = -3e38f;
        int i1 = 0, i2 = 0;
#pragma unroll
        for (int k = 0; k < 8; ++k) {
            int col4 = (k << 6) + (tc << 2);
#pragma unroll
            for (int e = 0; e < 4; ++e) {
                float sv = sc[k][e];
                float z  = sv + g[k][e];
                int c = col4 + e;
                if (z > z1)      { z2 = z1; i2 = i1; z1 = z; i1 = c; }
                else if (z > z2) { z2 = z;  i2 = c; }
                float ev = __expf(sv - sm);
                sc[k][e] = ev;
                sum += ev;
            }
        }
#pragma unroll
        for (int off = 1; off < 16; off <<= 1) {
            sum += __shfl_xor(sum, off);
            float oz1 = __shfl_xor(z1, off);
            int   oi1 = __shfl_xor(i1, off);
            float oz2 = __shfl_xor(z2, off);
            int   oi2 = __shfl_xor(i2, off);
            if (better(oz1, oi1, z1, i1)) {
                float nz2; int ni2;
                if (better(z1, i1, oz2, oi2)) { nz2 = z1;  ni2 = i1; }
                else                          { nz2 = oz2; ni2 = oi2; }
                z1 = oz1; i1 = oi1; z2 = nz2; i2 = ni2;
            } else if (better(oz1, oi1, z2, i2)) { z2 = oz1; i2 = oi1; }
        }
        float inv = 1.0f / sum;
        float* dp = dist + (size_t)gr * 512 + (tc << 2);
#pragma unroll
        for (int k = 0; k < 8; ++k)
            *(floatx4*)(dp + (k << 6)) = sc[k] * inv;
        if (tc == 0) { fZ1[row] = z1; fI1[row] = i1; fZ2[row] = z2; fI2[row] = i2; }
        __syncthreads();
    }

    // ---- final: 16 rows per wave: near-tie fallback + out = E[idx] ----
    for (int j = 0; j < 16; ++j) {
        int row = (wv << 4) + j;
        int gr  = row0 + row;
        float Z1 = fZ1[row], Z2 = fZ2[row];
        int   I1 = fI1[row], I2 = fI2[row];
        int idxF = I1;
        if (Z1 - Z2 < GAP_T) {
            const float* xr  = X + (size_t)gr * 512 + (lane << 3);
            floatx4 x0 = *(const floatx4*)xr;
            floatx4 x1 = *(const floatx4*)(xr + 4);
            const float* e1p = E + (size_t)I1 * 512 + (lane << 3);
            const float* e2p = E + (size_t)I2 * 512 + (lane << 3);
            floatx4 a0 = *(const floatx4*)e1p, a1 = *(const floatx4*)(e1p + 4);
            floatx4 b0 = *(const floatx4*)e2p, b1 = *(const floatx4*)(e2p + 4);
            float d1 = x0.x*a0.x + x0.y*a0.y + x0.z*a0.z + x0.w*a0.w
                     + x1.x*a1.x + x1.y*a1.y + x1.z*a1.z + x1.w*a1.w;
            float d2 = x0.x*b0.x + x0.y*b0.y + x0.z*b0.z + x0.w*b0.w
                     + x1.x*b1.x + x1.y*b1.y + x1.z*b1.z + x1.w*b1.w;
#pragma unroll
            for (int off = 1; off < 64; off <<= 1) {
                d1 += __shfl_xor(d1, off);
                d2 += __shfl_xor(d2, off);
            }
            float z1p = d1 * SCALE + G[(size_t)gr * 512 + I1];
            float z2p = d2 * SCALE + G[(size_t)gr * 512 + I2];
            if (z2p > z1p || (z2p == z1p && I2 < I1)) idxF = I2;
        }
        const float* er = E + (size_t)idxF * 512 + (lane << 3);
        floatx4 e0 = *(const floatx4*)er;
        floatx4 e1 = *(const floatx4*)(er + 4);
        float* o = outp + (size_t)gr * 512 + (lane << 3);
        *(floatx4*)o = e0;
        *(floatx4*)(o + 4) = e1;
    }
}

extern "C" void kernel_launch(void* const* d_in, const int* in_sizes, int n_in,
                              void* d_out, int out_size, void* d_ws, size_t ws_size,
                              hipStream_t stream) {
    const float* X = (const float*)d_in[0];
    const float* E = (const float*)d_in[1];
    const float* G = (const float*)d_in[2];
    float* outp = (float*)d_out;
    float* dist = outp + (size_t)N_ROWS * 512;
    uint32_t* bImg = (uint32_t*)d_ws;          // 512 KiB

    prep_b<<<512, 256, 0, stream>>>(E, bImg);
    fused<<<N_ROWS / 128, 512, 0, stream>>>(X, E, G, bImg, outp, dist);
}

// Round 13
// 255.965 us; speedup vs baseline: 3.0364x; 1.0154x over previous
//
#include <hip/hip_runtime.h>
#include <stdint.h>

typedef __attribute__((ext_vector_type(4))) float  floatx4;
typedef __attribute__((ext_vector_type(4))) uint32_t uintx4;
typedef __bf16 bf16x8 __attribute__((ext_vector_type(8)));

#define N_ROWS 131072
#define SCALE 0.044194173824159216f   /* 1/sqrt(512) */
#define GAP_T 1e-4f                   /* bf16-z worst-case err ~3e-5; margin 3x */

/* bank-spread slot for 64B rows: rows r..r+15 hit each 16B bank-group 2-way */
#define SLOT(c) ((((c) & 3) ^ (((c) >> 2) & 3)) << 4)

static __device__ __forceinline__ uint32_t bf16_rne(float x) {
    uint32_t u = __float_as_uint(x);
    return (u + 0x7FFFu + ((u >> 16) & 1u)) >> 16;
}

static __device__ __forceinline__ void gl_lds16(const void* g, void* l) {
    __builtin_amdgcn_global_load_lds(
        (const __attribute__((address_space(1))) void*)g,
        (__attribute__((address_space(3))) void*)l, 16, 0, 0);
}

static __device__ __forceinline__ bool better(float za, int ia, float zb, int ib) {
    return (za > zb) || (za == zb && ia < ib);
}

// ---------------------------------------------------------------------------
// Prep: E (f32 [512][512]) -> 16 pre-swizzled bf16 images of 32KB (k-chunks
// of 32). LDS layout: byte(c, kb) = c*64 + (kb ^ SLOT(c)), kb = 2*(k%32).
// ---------------------------------------------------------------------------
__global__ __launch_bounds__(256)
void prep_b(const float* __restrict__ E, uint32_t* __restrict__ bImg) {
    int w  = blockIdx.x * 256 + threadIdx.x;  // 0..131071 u32 words
    int ck = w >> 13;                          // 8192 words per 32KB image
    int o  = (w & 8191) << 2;                  // byte offset in image
    int c  = o >> 6;                           // code 0..511
    int kb = (o & 63) ^ SLOT(c);               // unswizzled k-byte
    int d  = (ck << 5) + (kb >> 1);
    float x0 = E[c * 512 + d];
    float x1 = E[c * 512 + d + 1];
    bImg[w] = bf16_rne(x0) | (bf16_rne(x1) << 16);
}

// ---------------------------------------------------------------------------
// Fused (R6/R12 anchor + T5 setprio around MFMA): block = 128 rows x 512
// codes, 8 waves (2 rg x 4 cg), wave = 64x128 (acc[4][8]).  2-phase
// double-buffered K-loop (16 steps of k=32).  Epilogue: 4 quarters of 32
// rows LDS-transposed to row-contiguous; softmax->dist, top2(s+g); final:
// near-tie exact-f32 fallback + out = E[idx] (straight-through val == 1.0).
// NOTE: this exact code shape keeps arch-VGPR at 64 (acc in AGPRs) -> 2
// blocks/CU.  Restructures (R7/R9/R10/R11) all inflated VGPR to ~128 and
// halved occupancy; do not modify COMPUTE/epilogue register lifetimes.
// ---------------------------------------------------------------------------
__global__ __launch_bounds__(512, 2)
void fused(const float* __restrict__ X, const float* __restrict__ E,
           const float* __restrict__ G, const uint32_t* __restrict__ bImg,
           float* __restrict__ outp, float* __restrict__ dist) {
    __shared__ uint8_t lds[81920];
    // K: B buf0 @0 (32K), B buf1 @32768, A buf0 @65536 (8K), A buf1 @73728
    // Epi: score quarter @0 (64K), stats @65536
    const int t    = threadIdx.x;
    const int lane = t & 63;
    const int l15  = lane & 15;
    const int q    = lane >> 4;
    const int wv   = t >> 6;
    const int rg   = wv >> 2;
    const int cg   = wv & 3;
    const int row0 = blockIdx.x << 7;

    floatx4 acc[4][8];
#pragma unroll
    for (int mi = 0; mi < 4; ++mi)
#pragma unroll
        for (int nc = 0; nc < 8; ++nc) acc[mi][nc] = (floatx4)0.0f;

    // ---- staging geometry ----
    const int r_ld = t >> 2;                 // A-stage row 0..127
    const int k8   = (t & 3) << 3;           // A-stage k elems (8)
    const float* xrow = X + (size_t)(row0 + r_ld) * 512 + k8;
    const int abyte = (r_ld << 6) + ((k8 << 1) ^ SLOT(r_ld));

#define STAGE_B(ck, par) {                                                   \
    const uint8_t* img_ = (const uint8_t*)bImg + ((ck) << 15);               \
    _Pragma("unroll")                                                        \
    for (int i_ = 0; i_ < 4; ++i_) {                                         \
        int off_ = (i_ << 13) + (t << 4);                                    \
        gl_lds16(img_ + off_, &lds[((par) << 15) + off_]);                   \
    } }

#define WRITE_A(v0, v1, par) {                                               \
    uintx4 hv_;                                                              \
    hv_.x = bf16_rne((v0).x) | (bf16_rne((v0).y) << 16);                     \
    hv_.y = bf16_rne((v0).z) | (bf16_rne((v0).w) << 16);                     \
    hv_.z = bf16_rne((v1).x) | (bf16_rne((v1).y) << 16);                     \
    hv_.w = bf16_rne((v1).z) | (bf16_rne((v1).w) << 16);                     \
    *(uintx4*)&lds[65536 + ((par) << 13) + abyte] = hv_; }

#define COMPUTE(par) {                                                       \
    const int boff_ = (par) << 15;                                           \
    const int aoff_ = 65536 + ((par) << 13);                                 \
    bf16x8 af_[4];                                                           \
    _Pragma("unroll")                                                        \
    for (int mi_ = 0; mi_ < 4; ++mi_) {                                      \
        int r_ = (rg << 6) + (mi_ << 4) + l15;                               \
        af_[mi_] = *(const bf16x8*)&lds[aoff_ + (r_ << 6) + ((q << 4) ^ SLOT(r_))]; \
    }                                                                        \
    __builtin_amdgcn_s_setprio(1);                                           \
    _Pragma("unroll")                                                        \
    for (int nc_ = 0; nc_ < 8; ++nc_) {                                      \
        int c_ = (cg << 7) + (nc_ << 4) + l15;                               \
        bf16x8 b_ = *(const bf16x8*)&lds[boff_ + (c_ << 6) + ((q << 4) ^ SLOT(c_))]; \
        _Pragma("unroll")                                                    \
        for (int mi_ = 0; mi_ < 4; ++mi_)                                    \
            acc[mi_][nc_] = __builtin_amdgcn_mfma_f32_16x16x32_bf16(af_[mi_], b_, acc[mi_][nc_], 0, 0, 0); \
    }                                                                        \
    __builtin_amdgcn_s_setprio(0); }

    // ---- prologue ----
    floatx4 xa0 = *(const floatx4*)(xrow);
    floatx4 xa1 = *(const floatx4*)(xrow + 4);
    STAGE_B(0, 0);
    WRITE_A(xa0, xa1, 0);
    floatx4 xb0 = *(const floatx4*)(xrow + 32);
    floatx4 xb1 = *(const floatx4*)(xrow + 36);
    __syncthreads();

    // ---- 2-phase pipeline, 16 steps ----
    for (int ck = 0; ck < 16; ck += 2) {
        if (ck + 1 < 16) { STAGE_B(ck + 1, 1); WRITE_A(xb0, xb1, 1); }
        if (ck + 2 < 16) {
            xa0 = *(const floatx4*)(xrow + ((ck + 2) << 5));
            xa1 = *(const floatx4*)(xrow + ((ck + 2) << 5) + 4);
        }
        COMPUTE(0);
        __syncthreads();
        if (ck + 2 < 16) { STAGE_B(ck + 2, 0); WRITE_A(xa0, xa1, 0); }
        if (ck + 3 < 16) {
            xb0 = *(const floatx4*)(xrow + ((ck + 3) << 5));
            xb1 = *(const floatx4*)(xrow + ((ck + 3) << 5) + 4);
        }
        COMPUTE(1);
        __syncthreads();
    }

#pragma unroll
    for (int mi = 0; mi < 4; ++mi)
#pragma unroll
        for (int nc = 0; nc < 8; ++nc) acc[mi][nc] *= SCALE;

    // -------- epilogue: 4 quarters of 32 rows ----------
    const int rp = t >> 4;    // 0..31 transposed row slot
    const int tc = t & 15;    // 16 threads per row

    float* fZ1 = (float*)(lds + 65536);          // [128]
    int*   fI1 = (int*)  (lds + 65536 + 512);
    float* fZ2 = (float*)(lds + 65536 + 1024);
    int*   fI2 = (int*)  (lds + 65536 + 1536);

#pragma unroll
    for (int Q = 0; Q < 4; ++Q) {
        if (rg == (Q >> 1)) {
#pragma unroll
            for (int m2 = 0; m2 < 2; ++m2) {
                int mi = ((Q & 1) << 1) + m2;
#pragma unroll
                for (int nc = 0; nc < 8; ++nc) {
                    int col = (cg << 7) + (nc << 4) + l15;
#pragma unroll
                    for (int p = 0; p < 4; ++p) {
                        int lr = (m2 << 4) + (q << 2) + p;   // 0..31
                        *(float*)&lds[(lr << 11) + ((col << 2) ^ ((lr & 7) << 4))] = acc[mi][nc][p];
                    }
                }
            }
        }
        __syncthreads();

        const int row = (Q << 5) + rp;           // local 0..127
        const int gr  = row0 + row;

        // issue G loads FIRST (latency hides under sm phase)
        const float* gp = G + (size_t)gr * 512 + (tc << 2);
        floatx4 g[8];
#pragma unroll
        for (int k = 0; k < 8; ++k) g[k] = *(const floatx4*)(gp + (k << 6));

        floatx4 sc[8];
#pragma unroll
        for (int k = 0; k < 8; ++k) {
            int col4 = (k << 6) + (tc << 2);
            sc[k] = *(const floatx4*)&lds[(rp << 11) + ((col4 << 2) ^ ((rp & 7) << 4))];
        }

        float sm = -3e38f;
#pragma unroll
        for (int k = 0; k < 8; ++k)
            sm = fmaxf(sm, fmaxf(fmaxf(sc[k].x, sc[k].y), fmaxf(sc[k].z, sc[k].w)));
#pragma unroll
        for (int off = 1; off < 16; off <<= 1) sm = fmaxf(sm, __shfl_xor(sm, off));

        float sum = 0.0f, z1 = -3e38f, z2 = -3e38f;
        int i1 = 0, i2 = 0;
#pragma unroll
        for (int k = 0; k < 8; ++k) {
            int col4 = (k << 6) + (tc << 2);
#pragma unroll
            for (int e = 0; e < 4; ++e) {
                float sv = sc[k][e];
                float z  = sv + g[k][e];
                int c = col4 + e;
                if (z > z1)      { z2 = z1; i2 = i1; z1 = z; i1 = c; }
                else if (z > z2) { z2 = z;  i2 = c; }
                float ev = __expf(sv - sm);
                sc[k][e] = ev;
                sum += ev;
            }
        }
#pragma unroll
        for (int off = 1; off < 16; off <<= 1) {
            sum += __shfl_xor(sum, off);
            float oz1 = __shfl_xor(z1, off);
            int   oi1 = __shfl_xor(i1, off);
            float oz2 = __shfl_xor(z2, off);
            int   oi2 = __shfl_xor(i2, off);
            if (better(oz1, oi1, z1, i1)) {
                float nz2; int ni2;
                if (better(z1, i1, oz2, oi2)) { nz2 = z1;  ni2 = i1; }
                else                          { nz2 = oz2; ni2 = oi2; }
                z1 = oz1; i1 = oi1; z2 = nz2; i2 = ni2;
            } else if (better(oz1, oi1, z2, i2)) { z2 = oz1; i2 = oi1; }
        }
        float inv = 1.0f / sum;
        float* dp = dist + (size_t)gr * 512 + (tc << 2);
#pragma unroll
        for (int k = 0; k < 8; ++k)
            *(floatx4*)(dp + (k << 6)) = sc[k] * inv;
        if (tc == 0) { fZ1[row] = z1; fI1[row] = i1; fZ2[row] = z2; fI2[row] = i2; }
        __syncthreads();
    }

    // ---- final: 16 rows per wave: near-tie fallback + out = E[idx] ----
    for (int j = 0; j < 16; ++j) {
        int row = (wv << 4) + j;
        int gr  = row0 + row;
        float Z1 = fZ1[row], Z2 = fZ2[row];
        int   I1 = fI1[row], I2 = fI2[row];
        int idxF = I1;
        if (Z1 - Z2 < GAP_T) {
            const float* xr  = X + (size_t)gr * 512 + (lane << 3);
            floatx4 x0 = *(const floatx4*)xr;
            floatx4 x1 = *(const floatx4*)(xr + 4);
            const float* e1p = E + (size_t)I1 * 512 + (lane << 3);
            const float* e2p = E + (size_t)I2 * 512 + (lane << 3);
            floatx4 a0 = *(const floatx4*)e1p, a1 = *(const floatx4*)(e1p + 4);
            floatx4 b0 = *(const floatx4*)e2p, b1 = *(const floatx4*)(e2p + 4);
            float d1 = x0.x*a0.x + x0.y*a0.y + x0.z*a0.z + x0.w*a0.w
                     + x1.x*a1.x + x1.y*a1.y + x1.z*a1.z + x1.w*a1.w;
            float d2 = x0.x*b0.x + x0.y*b0.y + x0.z*b0.z + x0.w*b0.w
                     + x1.x*b1.x + x1.y*b1.y + x1.z*b1.z + x1.w*b1.w;
#pragma unroll
            for (int off = 1; off < 64; off <<= 1) {
                d1 += __shfl_xor(d1, off);
                d2 += __shfl_xor(d2, off);
            }
            float z1p = d1 * SCALE + G[(size_t)gr * 512 + I1];
            float z2p = d2 * SCALE + G[(size_t)gr * 512 + I2];
            if (z2p > z1p || (z2p == z1p && I2 < I1)) idxF = I2;
        }
        const float* er = E + (size_t)idxF * 512 + (lane << 3);
        floatx4 e0 = *(const floatx4*)er;
        floatx4 e1 = *(const floatx4*)(er + 4);
        float* o = outp + (size_t)gr * 512 + (lane << 3);
        *(floatx4*)o = e0;
        *(floatx4*)(o + 4) = e1;
    }
}

extern "C" void kernel_launch(void* const* d_in, const int* in_sizes, int n_in,
                              void* d_out, int out_size, void* d_ws, size_t ws_size,
                              hipStream_t stream) {
    const float* X = (const float*)d_in[0];
    const float* E = (const float*)d_in[1];
    const float* G = (const float*)d_in[2];
    float* outp = (float*)d_out;
    float* dist = outp + (size_t)N_ROWS * 512;
    uint32_t* bImg = (uint32_t*)d_ws;          // 512 KiB

    prep_b<<<512, 256, 0, stream>>>(E, bImg);
    fused<<<N_ROWS / 128, 512, 0, stream>>>(X, E, G, bImg, outp, dist);
}